// Round 4
// baseline (585.570 us; speedup 1.0000x reference)
//
#include <hip/hip_runtime.h>
#include <hip/hip_fp16.h>
#include <cstdint>
#include <cstddef>

#define E_HID 256
#define R_HID 128
#define NREL  1000
#define EPSF  1e-16f

#define CH_BITS 12
#define CHUNK   (1 << CH_BITS)     // 4096 nodes per chunk (1 MB fp16 slice)
#define NCH     13                 // ceil(50000/4096)
#define NBIN    (NCH * NREL)       // 13000 (chunk-major, rel-minor keys)
#define RT      32                 // relations per tile
#define NRT     32                 // ceil(NREL/RT)
#define REP     16                 // edge-slice replicas per (table, rtile)
#define G5      (2 * NRT * REP)    // 1024 blocks = 4 per CU, all resident

typedef _Float16 f16x8 __attribute__((ext_vector_type(8)));
typedef float f32x4 __attribute__((ext_vector_type(4)));

struct alignas(16) h8 { __half2 a, b, c, d; };

// ================= K0: WcT[c][k] = fp16 of (c<128 ? Wh[k][c] : Wt[k][c-128])
__global__ __launch_bounds__(256) void k0_prep(
    const float* __restrict__ Wh, const float* __restrict__ Wt,
    __half* __restrict__ WcT)
{
  const int k = blockIdx.x;
  const int c = threadIdx.x;
  const float v = (c < R_HID) ? Wh[(size_t)k * R_HID + c]
                              : Wt[(size_t)k * R_HID + (c - R_HID)];
  WcT[(size_t)c * E_HID + k] = __float2half(v);
}

// ================= K1: MFMA fp16 GEMM (validated in R3) =====================
__global__ __launch_bounds__(256) void k1_gemm(
    const float* __restrict__ xe, const __half* __restrict__ WcT,
    const float* __restrict__ ah1, const float* __restrict__ ah2,
    const float* __restrict__ at1, const float* __restrict__ at2,
    __half* __restrict__ xhH, __half* __restrict__ xtH,
    float* __restrict__ sh1, float* __restrict__ sh2,
    float* __restrict__ st1, float* __restrict__ st2, int N)
{
  __shared__ __half As[128 * 32];
  __shared__ __half Bs[128 * 32];
  __shared__ float sA[2][128];
  __shared__ float sB[2][128];

  const int tid  = threadIdx.x;
  const int lane = tid & 63;
  const int wid  = tid >> 6;
  const int wr = wid >> 1, wc = wid & 1;
  const int nbm = (N + 127) >> 7;
  const int mb = blockIdx.x % nbm;
  const int cb = blockIdx.x / nbm;
  const int n0 = mb * 128;

  f32x4 acc[4][4];
  #pragma unroll
  for (int m = 0; m < 4; ++m)
    #pragma unroll
    for (int n = 0; n < 4; ++n) acc[m][n] = (f32x4){0.f, 0.f, 0.f, 0.f};

  const int arow = tid >> 1, ah = tid & 1;
  const bool aok = (n0 + arow) < N;
  const float*  xsrc = xe + (size_t)(n0 + arow) * E_HID + ah * 16;
  const __half* bsrc = WcT + ((size_t)(cb * 128 + arow) << 8) + ah * 16;
  __half* Aw = &As[arow * 32 + ah * 16];
  __half* Bw = &Bs[arow * 32 + ah * 16];

  const int fr = lane & 15, fq = lane >> 4;

  for (int kt = 0; kt < 8; ++kt) {
    __syncthreads();
    float4 v0 = make_float4(0,0,0,0), v1 = v0, v2 = v0, v3 = v0;
    if (aok) {
      const float* s = xsrc + kt * 32;
      v0 = *(const float4*)(s);     v1 = *(const float4*)(s + 4);
      v2 = *(const float4*)(s + 8); v3 = *(const float4*)(s + 12);
    }
    h8 p0, p1;
    p0.a = __floats2half2_rn(v0.x, v0.y); p0.b = __floats2half2_rn(v0.z, v0.w);
    p0.c = __floats2half2_rn(v1.x, v1.y); p0.d = __floats2half2_rn(v1.z, v1.w);
    p1.a = __floats2half2_rn(v2.x, v2.y); p1.b = __floats2half2_rn(v2.z, v2.w);
    p1.c = __floats2half2_rn(v3.x, v3.y); p1.d = __floats2half2_rn(v3.z, v3.w);
    *(h8*)(Aw) = p0; *(h8*)(Aw + 8) = p1;
    float4 b0 = *(const float4*)(bsrc + kt * 32);
    float4 b1 = *(const float4*)(bsrc + kt * 32 + 8);
    *(float4*)(Bw) = b0; *(float4*)(Bw + 8) = b1;
    __syncthreads();
    f16x8 aF[4], bF[4];
    #pragma unroll
    for (int m = 0; m < 4; ++m)
      aF[m] = *(const f16x8*)&As[(wr * 64 + m * 16 + fr) * 32 + fq * 8];
    #pragma unroll
    for (int n = 0; n < 4; ++n)
      bF[n] = *(const f16x8*)&Bs[(wc * 64 + n * 16 + fr) * 32 + fq * 8];
    #pragma unroll
    for (int m = 0; m < 4; ++m)
      #pragma unroll
      for (int n = 0; n < 4; ++n)
        acc[m][n] = __builtin_amdgcn_mfma_f32_16x16x32_f16(aF[m], bF[n], acc[m][n], 0, 0, 0);
  }

  __half* dst = (cb == 0) ? xhH : xtH;
  #pragma unroll
  for (int m = 0; m < 4; ++m) {
    const int rl0 = wr * 64 + m * 16 + fq * 4;
    #pragma unroll
    for (int r = 0; r < 4; ++r) {
      const int node = n0 + rl0 + r;
      if (node < N) {
        #pragma unroll
        for (int n = 0; n < 4; ++n)
          dst[(size_t)node * R_HID + wc * 64 + n * 16 + fr] = __float2half(acc[m][n][r]);
      }
    }
  }

  const float* aV1 = (cb == 0) ? ah1 : ah2;
  const float* aV2 = (cb == 0) ? at1 : at2;
  float avA[4], avB[4];
  #pragma unroll
  for (int n = 0; n < 4; ++n) {
    avA[n] = aV1[wc * 64 + n * 16 + fr];
    avB[n] = aV2[wc * 64 + n * 16 + fr];
  }
  #pragma unroll
  for (int m = 0; m < 4; ++m)
    #pragma unroll
    for (int r = 0; r < 4; ++r) {
      float vA = acc[m][0][r]*avA[0] + acc[m][1][r]*avA[1]
               + acc[m][2][r]*avA[2] + acc[m][3][r]*avA[3];
      float vB = acc[m][0][r]*avB[0] + acc[m][1][r]*avB[1]
               + acc[m][2][r]*avB[2] + acc[m][3][r]*avB[3];
      #pragma unroll
      for (int ofs = 1; ofs < 16; ofs <<= 1) {
        vA += __shfl_xor(vA, ofs, 16);
        vB += __shfl_xor(vB, ofs, 16);
      }
      if (fr == 0) {
        const int rl = wr * 64 + m * 16 + fq * 4 + r;
        sA[wc][rl] = vA;
        sB[wc][rl] = vB;
      }
    }
  __syncthreads();
  if (tid < 128 && n0 + tid < N) {
    float* o1 = (cb == 0) ? sh1 : sh2;
    float* o2 = (cb == 0) ? st1 : st2;
    o1[n0 + tid] = sA[0][tid] + sA[1][tid];
    o2[n0 + tid] = sB[0][tid] + sB[1][tid];
  }
}

// ================= K2: (chunk,rel)-key histograms for both lists ============
__global__ __launch_bounds__(256) void k2_hist(
    const int* __restrict__ ei, const int* __restrict__ rel,
    unsigned* __restrict__ cntH, unsigned* __restrict__ cntT, int E)
{
  for (int i = blockIdx.x * 256 + threadIdx.x; i < E; i += gridDim.x * 256) {
    const int r = rel[i];
    const int h = ei[i], t = ei[E + i];
    atomicAdd(cntH + (h >> CH_BITS) * NREL + r, 1u);
    atomicAdd(cntT + (t >> CH_BITS) * NREL + r, 1u);
  }
}

// ================= K3: one-block exclusive scan of both 13k-bin arrays ======
__global__ __launch_bounds__(1024) void k3_scan(
    const unsigned* __restrict__ cntH, const unsigned* __restrict__ cntT,
    unsigned* __restrict__ offsH, unsigned* __restrict__ offsT,
    unsigned* __restrict__ curH, unsigned* __restrict__ curT)
{
  __shared__ unsigned s[1024];
  const int t = threadIdx.x;
  for (int list = 0; list < 2; ++list) {
    const unsigned* cnt = list ? cntT : cntH;
    unsigned* offs = list ? offsT : offsH;
    unsigned* cur  = list ? curT  : curH;
    unsigned carry = 0u;
    for (int base = 0; base < NBIN; base += 1024) {
      const int idx = base + t;
      const unsigned v = (idx < NBIN) ? cnt[idx] : 0u;
      s[t] = v;
      __syncthreads();
      for (int ofs = 1; ofs < 1024; ofs <<= 1) {
        unsigned add = (t >= ofs) ? s[t - ofs] : 0u;
        __syncthreads();
        s[t] += add;
        __syncthreads();
      }
      if (idx < NBIN) {
        const unsigned excl = carry + s[t] - v;
        offs[idx] = excl;
        cur[idx]  = excl;
      }
      carry += s[1023];
      __syncthreads();
    }
    if (t == 0) offs[NBIN] = carry;
    __syncthreads();
  }
}

// ================= K4: scatter into (chunk,rel)-sorted meta lists ===========
// meta = { off(12b) | rl(5b) << 12 , weight as f32 bits }
__global__ __launch_bounds__(256) void k4_scatter(
    const int* __restrict__ ei, const int* __restrict__ rel,
    const float* __restrict__ sh1, const float* __restrict__ sh2,
    const float* __restrict__ st1, const float* __restrict__ st2,
    unsigned* __restrict__ curH, unsigned* __restrict__ curT,
    uint2* __restrict__ metaH, uint2* __restrict__ metaT, int E)
{
  for (int i = blockIdx.x * 256 + threadIdx.x; i < E; i += gridDim.x * 256) {
    const int h = ei[i], t = ei[E + i], r = rel[i];
    const float e1 = sh1[h] + sh2[t];
    const float e2 = st1[h] + st2[t];
    const float l1 = e1 >= 0.f ? e1 : 0.01f * e1;
    const float l2 = e2 >= 0.f ? e2 : 0.01f * e2;
    const float w1 = expf(l1);
    const float w2 = expf(l2);
    const unsigned pH = atomicAdd(curH + (h >> CH_BITS) * NREL + r, 1u);
    metaH[pH] = make_uint2((unsigned)((h & (CHUNK - 1)) | ((r & (RT - 1)) << CH_BITS)),
                           __float_as_uint(w1));
    const unsigned pT = atomicAdd(curT + (t >> CH_BITS) * NREL + r, 1u);
    metaT[pT] = make_uint2((unsigned)((t & (CHUNK - 1)) | ((r & (RT - 1)) << CH_BITS)),
                           __float_as_uint(w2));
  }
}

// ================= K5: chunk-phased gather-reduce, LDS rel-tile acc =========
// grid = 2 tables x 32 rtiles x 16 reps = 1024 blocks (4/CU, all resident).
// All blocks sweep chunks 0..NCH-1 in the same order -> per-XCD L2 working
// set ~= 2 active 1MB slices. Register acc per rel-run, LDS atomic on change.
#define FLUSH() do { \
    if (curRl >= 0) { \
      atomicAdd(&acc[curRl * 129 + 2 * lane],     a0); \
      atomicAdd(&acc[curRl * 129 + 2 * lane + 1], a1); \
      if (lane == 0) atomicAdd(&accS[curRl], sw); \
    } a0 = 0.f; a1 = 0.f; sw = 0.f; } while (0)

#define EDGE(MV, VV) do { \
    const int rl = (int)(MV.x >> CH_BITS); \
    const float w = __uint_as_float(MV.y); \
    if (rl != curRl) { FLUSH(); curRl = rl; } \
    const float2 f = __half22float2(VV); \
    a0 += w * f.x; a1 += w * f.y; sw += w; } while (0)

__global__ __launch_bounds__(256) void k5_reduce(
    const unsigned* __restrict__ offsH, const unsigned* __restrict__ offsT,
    const uint2* __restrict__ metaH, const uint2* __restrict__ metaT,
    const __half* __restrict__ xhH, const __half* __restrict__ xtH,
    float* __restrict__ part, float* __restrict__ partS)
{
  __shared__ float acc[RT * 129];
  __shared__ float accS[RT];
  const int tid  = threadIdx.x;
  const int lane = tid & 63;
  const int wv   = tid >> 6;
  const int bid  = blockIdx.x;
  const int table = bid >> 9;
  const int rtile = (bid >> 4) & 31;
  const int rep   = bid & 15;

  for (int i = tid; i < RT * 129; i += 256) acc[i] = 0.f;
  if (tid < RT) accS[tid] = 0.f;
  __syncthreads();

  const unsigned* offs = table ? offsT : offsH;
  const uint2*    meta = table ? metaT : metaH;
  const __half*   xsrc = table ? xtH   : xhH;
  const int r0   = rtile * RT;
  const int rend = (r0 + RT < NREL) ? r0 + RT : NREL;

  float a0 = 0.f, a1 = 0.f, sw = 0.f;
  int curRl = -1;

  for (int c = 0; c < NCH; ++c) {
    const unsigned s0 = offs[c * NREL + r0];
    const unsigned s1 = offs[c * NREL + rend];
    const unsigned len = s1 - s0;
    const unsigned b0 = s0 + ((len * (unsigned)rep) >> 4);
    const unsigned b1 = s0 + ((len * (unsigned)(rep + 1)) >> 4);
    const unsigned wl = b1 - b0;
    unsigned p        = b0 + ((wl * (unsigned)wv) >> 2);
    const unsigned pe = b0 + ((wl * (unsigned)(wv + 1)) >> 2);
    const __half* xb = xsrc + (((size_t)c << CH_BITS) * R_HID) + 2 * lane;

    for (; p + 4 <= pe; p += 4) {
      const uint2 m0 = meta[p],     m1 = meta[p + 1];
      const uint2 m2 = meta[p + 2], m3 = meta[p + 3];
      const __half2 v0 = *(const __half2*)(xb + (size_t)(m0.x & (CHUNK - 1)) * R_HID);
      const __half2 v1 = *(const __half2*)(xb + (size_t)(m1.x & (CHUNK - 1)) * R_HID);
      const __half2 v2 = *(const __half2*)(xb + (size_t)(m2.x & (CHUNK - 1)) * R_HID);
      const __half2 v3 = *(const __half2*)(xb + (size_t)(m3.x & (CHUNK - 1)) * R_HID);
      EDGE(m0, v0); EDGE(m1, v1); EDGE(m2, v2); EDGE(m3, v3);
    }
    for (; p < pe; ++p) {
      const uint2 m = meta[p];
      const __half2 v = *(const __half2*)(xb + (size_t)(m.x & (CHUNK - 1)) * R_HID);
      EDGE(m, v);
    }
  }
  FLUSH();
  __syncthreads();

  float* pd = part + (size_t)bid * (RT * R_HID);
  for (int i = tid; i < RT * R_HID; i += 256)
    pd[i] = acc[(i >> 7) * 129 + (i & 127)];
  if (tid < RT) partS[bid * RT + tid] = accS[tid];
}

// ================= K6: reduce partials, finalize ============================
__global__ __launch_bounds__(128) void k6_final(
    const float* __restrict__ part, const float* __restrict__ partS,
    float* __restrict__ out)
{
  const int r = blockIdx.x;
  const int d = threadIdx.x;
  const int rtile = r >> 5, rl = r & (RT - 1);
  float s1 = 0.f, s2 = 0.f, oh = 0.f, ot = 0.f;
  #pragma unroll
  for (int rep = 0; rep < REP; ++rep) {
    const int pid0 = (rtile) * REP + rep;             // table 0
    const int pid1 = (NRT + rtile) * REP + rep;       // table 1
    oh += part[(size_t)pid0 * (RT * R_HID) + rl * R_HID + d];
    ot += part[(size_t)pid1 * (RT * R_HID) + rl * R_HID + d];
    s1 += partS[pid0 * RT + rl];
    s2 += partS[pid1 * RT + rl];
  }
  out[r * R_HID + d] = oh / (s1 + EPSF) + ot / (s2 + EPSF);
}

extern "C" void kernel_launch(void* const* d_in, const int* in_sizes, int n_in,
                              void* d_out, int out_size, void* d_ws, size_t ws_size,
                              hipStream_t stream) {
  const float* xe  = (const float*)d_in[0];
  const int*   ei  = (const int*)d_in[1];
  const int*   rel = (const int*)d_in[2];
  const float* Wh  = (const float*)d_in[3];
  const float* Wt  = (const float*)d_in[4];
  const float* ah1 = (const float*)d_in[5];
  const float* ah2 = (const float*)d_in[6];
  const float* at1 = (const float*)d_in[7];
  const float* at2 = (const float*)d_in[8];
  const int N = in_sizes[0] / E_HID;
  const int E = in_sizes[2];

  char* w = (char*)d_ws;
  size_t o = 0;
  auto alloc = [&](size_t bytes) -> void* {
    void* p = w + o;
    o = (o + bytes + 255) & ~(size_t)255;
    return p;
  };
  __half* WcT = (__half*)alloc((size_t)E_HID * E_HID * 2);
  __half* xhH = (__half*)alloc((size_t)N * R_HID * 2);
  __half* xtH = (__half*)alloc((size_t)N * R_HID * 2);
  float* sh1 = (float*)alloc((size_t)N * 4);
  float* sh2 = (float*)alloc((size_t)N * 4);
  float* st1 = (float*)alloc((size_t)N * 4);
  float* st2 = (float*)alloc((size_t)N * 4);
  uint2* metaH = (uint2*)alloc((size_t)E * 8);
  uint2* metaT = (uint2*)alloc((size_t)E * 8);
  unsigned* offsH = (unsigned*)alloc((size_t)(NBIN + 1) * 4);
  unsigned* offsT = (unsigned*)alloc((size_t)(NBIN + 1) * 4);
  float* part  = (float*)alloc((size_t)G5 * RT * R_HID * 4);
  float* partS = (float*)alloc((size_t)G5 * RT * 4);
  const size_t zstart = o;  // zero-init region: counters
  unsigned* cntH = (unsigned*)alloc((size_t)NBIN * 4);
  unsigned* cntT = (unsigned*)alloc((size_t)NBIN * 4);
  unsigned* curH = (unsigned*)alloc((size_t)NBIN * 4);
  unsigned* curT = (unsigned*)alloc((size_t)NBIN * 4);
  const size_t zbytes = o - zstart;

  hipMemsetAsync(w + zstart, 0, zbytes, stream);

  const int nbm = (N + 127) >> 7;
  k0_prep<<<E_HID, 256, 0, stream>>>(Wh, Wt, WcT);
  k1_gemm<<<nbm * 2, 256, 0, stream>>>(xe, WcT, ah1, ah2, at1, at2,
                                       xhH, xtH, sh1, sh2, st1, st2, N);
  k2_hist<<<1024, 256, 0, stream>>>(ei, rel, cntH, cntT, E);
  k3_scan<<<1, 1024, 0, stream>>>(cntH, cntT, offsH, offsT, curH, curT);
  k4_scatter<<<1024, 256, 0, stream>>>(ei, rel, sh1, sh2, st1, st2,
                                       curH, curT, metaH, metaT, E);
  k5_reduce<<<G5, 256, 0, stream>>>(offsH, offsT, metaH, metaT, xhH, xtH,
                                    part, partS);
  k6_final<<<NREL, 128, 0, stream>>>(part, partS, (float*)d_out);
}